// Round 11
// baseline (214.640 us; speedup 1.0000x reference)
//
#include <hip/hip_runtime.h>
#include <hip/hip_bf16.h>

// SingleHeadAttention: embedded [4,4096,1024] f32; Wk/Wq/Wv [128,1024] f32.
// out = causal_softmax((emb Wq^T)(emb Wk^T)^T / sqrt(128)) (emb Wv^T), f32.
//
// R11 = R10 (zero-LDS zero-barrier attn, frag-ordered ws — verified: LDS=0,
// conflicts=0, coalesced) with ONE change: SPLIT=8 -> grid 1024 = 4 blocks/CU
// (16 waves/CU) + __launch_bounds__(256,4). R7-R10 all plateau at 71-84us with
// every pipe <15% busy at 2 blocks/CU: pure latency-bound; this doubles the
// wave-level interleave. R8 proved ws >= ~45MB (its SPLIT=8 branch ran).
// Frag layouts (HW-verified R2-R10): A/B frag idx=lane&15, k=quad*8+j (K=32)
// or quad*4+j (K=16); D col(lane&15)=B's n, row(quad*4+reg)=A's m.
//  Qf/Kf[((b*256 + s16)*4 + kf)*64 + lane] x bf16x8   (s16 = seq/16)
//  Vf[(((b*64 + t64)*8 + ht)*4 + nt)*64 + lane] x f16x4 (t64 = seq/64)

#define SEQ 4096
#define BATCH 4
#define HS 128
#define PSTRIDE ((size_t)BATCH * SEQ * HS)   // u16 elems per split partial

typedef unsigned short u16;
typedef __bf16 bf16x8 __attribute__((ext_vector_type(8)));
typedef _Float16 f16x4 __attribute__((ext_vector_type(4)));
typedef float f32x4 __attribute__((ext_vector_type(4)));

__device__ __forceinline__ u16 f2bf(float f) {
    union { float f; unsigned u; } v; v.f = f;
    unsigned u = v.u;
    return (u16)((u + 0x7FFFu + ((u >> 16) & 1u)) >> 16);  // RNE, finite
}
__device__ __forceinline__ float bf2f(u16 u) {
    union { unsigned u; float f; } v; v.u = ((unsigned)u) << 16; return v.f;
}
__device__ __forceinline__ u16 f2h(float f) {
    union { _Float16 h; u16 u; } v; v.h = (_Float16)f; return v.u;
}

// ---------------- K0: W -> bf16, pre-tiled in B-frag order ----------------
__global__ __launch_bounds__(256) void wconv_kernel(
    const float* __restrict__ Wk, const float* __restrict__ Wq,
    const float* __restrict__ Wv, u16* __restrict__ Wt)
{
    const int g    = blockIdx.x * 256 + threadIdx.x;   // 0..49151
    const int lane = g & 63;
    const int kf   = (g >> 6) & 1;
    const int kc   = (g >> 7) & 15;
    const int nt   = g >> 11;
    const int row  = nt * 16 + (lane & 15);
    const int k0   = kc * 64 + kf * 32 + (lane >> 4) * 8;
    const float* src = (row < 128) ? Wk : ((row < 256) ? Wq : Wv);
    const float scale = (row >= 128 && row < 256)
        ? 0.08838834764831845f * 1.4426950408889634f : 1.0f;
    const float4 v0 = *(const float4*)&src[(size_t)(row & 127) * 1024 + k0];
    const float4 v1 = *(const float4*)&src[(size_t)(row & 127) * 1024 + k0 + 4];
    ushort4 a, b;
    a.x = f2bf(v0.x * scale); a.y = f2bf(v0.y * scale);
    a.z = f2bf(v0.z * scale); a.w = f2bf(v0.w * scale);
    b.x = f2bf(v1.x * scale); b.y = f2bf(v1.y * scale);
    b.z = f2bf(v1.z * scale); b.w = f2bf(v1.w * scale);
    *(ushort4*)&Wt[(size_t)g * 8]     = a;
    *(ushort4*)&Wt[(size_t)g * 8 + 4] = b;
}

// ---------------- K1: QKV projection -> frag-ordered outputs ----------------
// grid 512 x 256 (2 blocks/CU). Block: 32 emb rows x 384 cols; wave: 96 cols.
__global__ __launch_bounds__(256, 2) void qkv_kernel(
    const float* __restrict__ emb, const u16* __restrict__ Wt,
    u16* __restrict__ Qf, u16* __restrict__ Kf, u16* __restrict__ Vf)
{
    __shared__ u16 sE[2][32][72];
    __shared__ u16 sOut[32][392];   // cols 0-127 K(bf16), 128-255 Q(bf16), 256-383 V(f16)

    const int tid  = threadIdx.x;
    const int wv   = tid >> 6;
    const int lane = tid & 63;
    const int quad = lane >> 4;
    const int l16  = lane & 15;
    const int R0   = blockIdx.x * 32;

    const int arow = tid >> 3, ac8 = tid & 7;     // A-stage: 16B/thread/chunk
    const float* abase = &emb[(size_t)(R0 + arow) * 1024 + ac8 * 8];

    f32x4 acc[2][6];
    #pragma unroll
    for (int rg = 0; rg < 2; rg++)
        #pragma unroll
        for (int nt = 0; nt < 6; nt++) acc[rg][nt] = (f32x4){0.f, 0.f, 0.f, 0.f};

    bf16x8 B0[12], B1[12];

#define LOADB(kci, B)                                                          \
    {                                                                          \
        _Pragma("unroll")                                                      \
        for (int nt = 0; nt < 6; nt++) {                                       \
            const size_t g = ((size_t)((wv * 6 + nt) * 16 + (kci)) * 2) * 64 + lane; \
            B[2 * nt]     = *(const bf16x8*)&Wt[g * 8];                        \
            B[2 * nt + 1] = *(const bf16x8*)&Wt[(g + 64) * 8];                 \
        }                                                                      \
    }
#define WRITEA(buf, v0, v1)                                                    \
    {                                                                          \
        ushort4 lo, hi;                                                        \
        lo.x = f2bf((v0).x); lo.y = f2bf((v0).y);                              \
        lo.z = f2bf((v0).z); lo.w = f2bf((v0).w);                              \
        hi.x = f2bf((v1).x); hi.y = f2bf((v1).y);                              \
        hi.z = f2bf((v1).z); hi.w = f2bf((v1).w);                              \
        *(ushort4*)&sE[buf][arow][ac8 * 8]     = lo;                           \
        *(ushort4*)&sE[buf][arow][ac8 * 8 + 4] = hi;                           \
    }
#define COMPUTE(buf, B)                                                        \
    {                                                                          \
        bf16x8 a[2][2];                                                        \
        _Pragma("unroll")                                                      \
        for (int rg = 0; rg < 2; rg++)                                         \
            _Pragma("unroll")                                                  \
            for (int kf = 0; kf < 2; kf++)                                     \
                a[rg][kf] = *(const bf16x8*)&sE[buf][rg * 16 + l16][kf * 32 + quad * 8]; \
        _Pragma("unroll")                                                      \
        for (int nt = 0; nt < 6; nt++)                                         \
            _Pragma("unroll")                                                  \
            for (int rg = 0; rg < 2; rg++) {                                   \
                acc[rg][nt] = __builtin_amdgcn_mfma_f32_16x16x32_bf16(a[rg][0], B[2 * nt],     acc[rg][nt], 0, 0, 0); \
                acc[rg][nt] = __builtin_amdgcn_mfma_f32_16x16x32_bf16(a[rg][1], B[2 * nt + 1], acc[rg][nt], 0, 0, 0); \
            }                                                                  \
    }

    float4 av0 = *(const float4*)&abase[0];
    float4 av1 = *(const float4*)&abase[4];
    LOADB(0, B0);
    WRITEA(0, av0, av1);

    for (int it = 0; it < 8; it++) {
        const int k1 = 2 * it + 1;
        __syncthreads();
        av0 = *(const float4*)&abase[k1 * 64];
        av1 = *(const float4*)&abase[k1 * 64 + 4];
        LOADB(k1, B1);
        COMPUTE(0, B0);
        WRITEA(1, av0, av1);
        __syncthreads();
        if (it < 7) {
            av0 = *(const float4*)&abase[(k1 + 1) * 64];
            av1 = *(const float4*)&abase[(k1 + 1) * 64 + 4];
            LOADB(k1 + 1, B0);
        }
        COMPUTE(1, B1);
        if (it < 7) WRITEA(0, av0, av1);
    }

    // ---- epilogue: acc -> sOut scatter -> frag-ordered coalesced stores ----
    #pragma unroll
    for (int nt = 0; nt < 6; nt++) {
        const int col = wv * 96 + nt * 16 + l16;
        #pragma unroll
        for (int rg = 0; rg < 2; rg++) {
            const int rl = rg * 16 + quad * 4;
            #pragma unroll
            for (int r = 0; r < 4; r++) {
                const float v = acc[rg][nt][r];
                sOut[rl + r][col] = (col < 256) ? f2bf(v) : f2h(v);
            }
        }
    }
    __syncthreads();

    const int b  = R0 >> 12;
    const int s0 = R0 & 4095;
    // K and Q frag-order: bf16x8 groups, contiguous 1KB wave stores
    #pragma unroll
    for (int i = 0; i < 2; i++) {
        const int g    = tid + i * 256;          // 0..511
        const int lg   = g & 63;
        const int kfp  = (g >> 6) & 3;
        const int k16l = g >> 8;                 // 0..1
        const int rl   = k16l * 16 + (lg & 15);
        const int cl   = kfp * 32 + (lg >> 4) * 8;
        const size_t base = (((size_t)(b * 256 + (s0 >> 4) + k16l) * 4 + kfp) * 64 + lg) * 8;
        *(uint4*)&Kf[base] = *(const uint4*)&sOut[rl][cl];
        *(uint4*)&Qf[base] = *(const uint4*)&sOut[rl][128 + cl];
    }
    // V frag-order: f16x4 groups, contiguous 512B wave stores
    #pragma unroll
    for (int i = 0; i < 4; i++) {
        const int g   = tid + i * 256;           // 0..1023
        const int lg  = g & 63;
        const int ntl = (g >> 6) & 1;
        const int ht  = g >> 7;                  // 0..7
        const int h   = ht * 16 + (lg & 15);
        const int kl  = ntl * 16 + ((lg >> 4) & 3) * 4;
        ushort4 o;
        o.x = sOut[kl + 0][256 + h];
        o.y = sOut[kl + 1][256 + h];
        o.z = sOut[kl + 2][256 + h];
        o.w = sOut[kl + 3][256 + h];
        const int t64 = s0 >> 6;
        const int ntg = ((s0 >> 4) & 3) + ntl;
        const size_t base = ((((size_t)(b * 64 + t64) * 8 + ht) * 4 + ntg) * 64 + lg) * 4;
        *(ushort4*)&Vf[base] = o;
    }
#undef LOADB
#undef WRITEA
#undef COMPUTE
}

// ---------------- K2: zero-LDS zero-barrier flash attention ----------------
// grid 32*BATCH*SPLIT x 256; SPLIT=8 -> 1024 blocks = 4/CU = 16 waves/CU.
// All fragment loads are contiguous wave-loads from frag-ordered ws (L2-hot).
template<int SPLIT>
__global__ __launch_bounds__(256, 4) void attn_kernel(
    const u16* __restrict__ Qf, const u16* __restrict__ Kf,
    const u16* __restrict__ Vf, u16* __restrict__ Opart,
    float* __restrict__ lpart, float* __restrict__ out)
{
    const int tid  = threadIdx.x;
    const int wv   = tid >> 6;
    const int lane = tid & 63;
    const int quad = lane >> 4;
    const int l16  = lane & 15;

    const int L = blockIdx.x;
    const int b = L & 3;
    const int u = L >> 2;
    int Q, sp;
    if constexpr (SPLIT == 1) {
        Q = u; sp = 0;
    } else {
        constexpr int half = SPLIT / 2;
        if (u < 32 * half) { Q = u / half; sp = u % half; }
        else { const int v = u - 32 * half; Q = 31 - v / half; sp = half + v % half; }
    }
    const int q0 = Q * 128;
    const int ktmax = 2 * Q + 1;
    const size_t bS = (size_t)b * SEQ;

    const u16* Kb = Kf + (size_t)b * 256 * 4 * 64 * 8;
    const u16* Vb = Vf + (size_t)b * 64 * 8 * 4 * 64 * 4;

    // Q fragments from frag-ordered Qf (coalesced 1KB wave loads)
    bf16x8 qf[2][4];
    #pragma unroll
    for (int qg = 0; qg < 2; qg++) {
        const int q16 = Q * 8 + wv * 2 + qg;
        #pragma unroll
        for (int kf = 0; kf < 4; kf++)
            qf[qg][kf] = *(const bf16x8*)&Qf[(((size_t)(b * 256 + q16) * 4 + kf) * 64 + lane) * 8];
    }

    float rs0 = 0.f, rs1 = 0.f;
    f32x4 O[2][8];   // O^T: col=q=l16, row=h=ht*16+quad*4+reg
    #pragma unroll
    for (int qg = 0; qg < 2; qg++)
        #pragma unroll
        for (int ht = 0; ht < 8; ht++) O[qg][ht] = (f32x4){0.f, 0.f, 0.f, 0.f};

    const int qg0 = q0 + wv * 32 + l16;   // qg=1 row is qg0+16

    for (int kt = sp; kt <= ktmax; kt += SPLIT) {
        const int kb = kt * 64;
        const bool diag = (kt >= 2 * Q);
        f16x4 pf0[4], pf1[4];
        #pragma unroll
        for (int nt = 0; nt < 4; nt++) {   // stream S-tile -> p
            f32x4 s0 = (f32x4){0.f, 0.f, 0.f, 0.f};
            f32x4 s1 = (f32x4){0.f, 0.f, 0.f, 0.f};
            const size_t kbase = ((size_t)(kt * 4 + nt) * 4) * 64 * 8;
            #pragma unroll
            for (int kf = 0; kf < 4; kf++) {
                const bf16x8 kfr = *(const bf16x8*)&Kb[kbase + ((size_t)kf * 64 + lane) * 8];
                s0 = __builtin_amdgcn_mfma_f32_16x16x32_bf16(kfr, qf[0][kf], s0, 0, 0, 0);
                s1 = __builtin_amdgcn_mfma_f32_16x16x32_bf16(kfr, qf[1][kf], s1, 0, 0, 0);
            }
            if (diag) {
                #pragma unroll
                for (int r = 0; r < 4; r++) {
                    const int kg = kb + nt * 16 + quad * 4 + r;
                    if (kg > qg0)      s0[r] = -3.0e38f;
                    if (kg > qg0 + 16) s1[r] = -3.0e38f;
                }
            }
            f16x4 p0, p1;
            #pragma unroll
            for (int r = 0; r < 4; r++) {
                const float e0 = exp2f(s0[r] - 4.0f);   // scores in log2 domain
                const float e1 = exp2f(s1[r] - 4.0f);
                rs0 += e0; rs1 += e1;
                p0[r] = (_Float16)e0; p1[r] = (_Float16)e1;
            }
            pf0[nt] = p0; pf1[nt] = p1;
        }

        // O^T += V^T·P^T : V A-frags coalesced 512B wave loads
        const size_t vtbase = ((size_t)kt * 8) * 4 * 64 * 4;
        #pragma unroll
        for (int ht = 0; ht < 8; ht++) {
            f16x4 vf[4];
            #pragma unroll
            for (int nt = 0; nt < 4; nt++)
                vf[nt] = *(const f16x4*)&Vb[vtbase + (((size_t)ht * 4 + nt) * 64 + lane) * 4];
            #pragma unroll
            for (int nt = 0; nt < 4; nt++) {
                O[0][ht] = __builtin_amdgcn_mfma_f32_16x16x16f16(vf[nt], pf0[nt], O[0][ht], 0, 0, 0);
                O[1][ht] = __builtin_amdgcn_mfma_f32_16x16x16f16(vf[nt], pf1[nt], O[1][ht], 0, 0, 0);
            }
        }
    }

    rs0 += __shfl_xor(rs0, 16); rs0 += __shfl_xor(rs0, 32);
    rs1 += __shfl_xor(rs1, 16); rs1 += __shfl_xor(rs1, 32);

    if constexpr (SPLIT == 1) {
        #pragma unroll
        for (int qg = 0; qg < 2; qg++) {
            const float inv = 1.0f / (qg ? rs1 : rs0);
            const int q = q0 + wv * 32 + qg * 16 + l16;
            #pragma unroll
            for (int ht = 0; ht < 8; ht++) {
                f32x4 o = O[qg][ht] * inv;
                *(f32x4*)&out[(bS + q) * HS + ht * 16 + quad * 4] = o;
            }
        }
    } else {
        // register-order slots: each wave store = 512B contiguous
        #pragma unroll
        for (int qg = 0; qg < 2; qg++)
            #pragma unroll
            for (int ht = 0; ht < 8; ht++) {
                const size_t j = ((size_t)((((b * 32 + Q) * 4 + wv) * 2 + qg) * 8 + ht)) * 64 + lane;
                ushort4 o;
                o.x = f2bf(O[qg][ht][0]); o.y = f2bf(O[qg][ht][1]);
                o.z = f2bf(O[qg][ht][2]); o.w = f2bf(O[qg][ht][3]);
                *(ushort4*)&Opart[(size_t)sp * PSTRIDE + j * 4] = o;
            }
        if (quad == 0) {
            lpart[((size_t)(sp * BATCH + b)) * SEQ + q0 + wv * 32 + l16]      = rs0;
            lpart[((size_t)(sp * BATCH + b)) * SEQ + q0 + wv * 32 + 16 + l16] = rs1;
        }
    }
}

// ---------------- K3: merge split partials ----------------
template<int SPLIT>
__global__ __launch_bounds__(256) void merge_kernel(
    const u16* __restrict__ Opart, const float* __restrict__ lpart,
    float* __restrict__ out)
{
    const int g  = blockIdx.x * 256 + threadIdx.x;   // one float4 of out
    const int b  = g >> 17;
    const int q  = (g >> 5) & 4095;
    const int hc = g & 31;
    const int Qb = q >> 7, wvv = (q >> 5) & 3, qg = (q >> 4) & 1, l16 = q & 15;
    const int ht = hc >> 2, qd = hc & 3;
    const int lane = qd * 16 + l16;
    const size_t j4 = (((size_t)((((b * 32 + Qb) * 4 + wvv) * 2 + qg) * 8 + ht)) * 64 + lane) * 4;

    float den = 0.f;
    f32x4 num = (f32x4){0.f, 0.f, 0.f, 0.f};
    #pragma unroll
    for (int s = 0; s < SPLIT; s++) {
        den += lpart[((size_t)(s * BATCH + b)) * SEQ + q];
        const ushort4 o = *(const ushort4*)&Opart[(size_t)s * PSTRIDE + j4];
        num[0] += bf2f(o.x); num[1] += bf2f(o.y);
        num[2] += bf2f(o.z); num[3] += bf2f(o.w);
    }
    const float inv = 1.0f / den;
    float4 o; o.x = num[0] * inv; o.y = num[1] * inv;
    o.z = num[2] * inv; o.w = num[3] * inv;
    *(float4*)&out[(size_t)g * 4] = o;
}

extern "C" void kernel_launch(void* const* d_in, const int* in_sizes, int n_in,
                              void* d_out, int out_size, void* d_ws, size_t ws_size,
                              hipStream_t stream) {
    const float* emb = (const float*)d_in[0];
    const float* Wk  = (const float*)d_in[1];
    const float* Wq  = (const float*)d_in[2];
    const float* Wv  = (const float*)d_in[3];
    float* out = (float*)d_out;

    char* ws = (char*)d_ws;
    const size_t WBF_SZ    = (size_t)384 * 1024 * 2;
    const size_t QKV_SZ    = (size_t)BATCH * SEQ * HS * 2;   // 4 MB each
    const size_t Q_OFF     = WBF_SZ;
    const size_t K_OFF     = Q_OFF + QKV_SZ;
    const size_t V_OFF     = K_OFF + QKV_SZ;
    const size_t OPART_OFF = V_OFF + QKV_SZ;
    const size_t OPART_1   = PSTRIDE * 2;                    // 4 MB per split
    const size_t L_1       = (size_t)BATCH * SEQ * 4;        // 64 KB per split

    u16* Wt = (u16*)ws;
    u16* Qf = (u16*)(ws + Q_OFF);
    u16* Kf = (u16*)(ws + K_OFF);
    u16* Vf = (u16*)(ws + V_OFF);

    wconv_kernel<<<dim3(192), dim3(256), 0, stream>>>(Wk, Wq, Wv, Wt);
    qkv_kernel<<<dim3(512), dim3(256), 0, stream>>>(emb, Wt, Qf, Kf, Vf);

    const size_t need8 = OPART_OFF + 8 * (OPART_1 + L_1);
    const size_t need4 = OPART_OFF + 4 * (OPART_1 + L_1);
    const size_t need2 = OPART_OFF + 2 * (OPART_1 + L_1);

    if (ws_size >= need8) {
        u16*   Opart = (u16*)(ws + OPART_OFF);
        float* lp    = (float*)(ws + OPART_OFF + 8 * OPART_1);
        attn_kernel<8><<<dim3(32 * BATCH * 8), dim3(256), 0, stream>>>(Qf, Kf, Vf, Opart, lp, out);
        merge_kernel<8><<<dim3(BATCH * SEQ * HS / 4 / 256), dim3(256), 0, stream>>>(Opart, lp, out);
    } else if (ws_size >= need4) {
        u16*   Opart = (u16*)(ws + OPART_OFF);
        float* lp    = (float*)(ws + OPART_OFF + 4 * OPART_1);
        attn_kernel<4><<<dim3(32 * BATCH * 4), dim3(256), 0, stream>>>(Qf, Kf, Vf, Opart, lp, out);
        merge_kernel<4><<<dim3(BATCH * SEQ * HS / 4 / 256), dim3(256), 0, stream>>>(Opart, lp, out);
    } else if (ws_size >= need2) {
        u16*   Opart = (u16*)(ws + OPART_OFF);
        float* lp    = (float*)(ws + OPART_OFF + 2 * OPART_1);
        attn_kernel<2><<<dim3(32 * BATCH * 2), dim3(256), 0, stream>>>(Qf, Kf, Vf, Opart, lp, out);
        merge_kernel<2><<<dim3(BATCH * SEQ * HS / 4 / 256), dim3(256), 0, stream>>>(Opart, lp, out);
    } else {
        attn_kernel<1><<<dim3(32 * BATCH), dim3(256), 0, stream>>>(Qf, Kf, Vf, nullptr, nullptr, out);
    }
}

// Round 12
// 162.739 us; speedup vs baseline: 1.3189x; 1.3189x over previous
//
#include <hip/hip_runtime.h>
#include <hip/hip_bf16.h>

// SingleHeadAttention: embedded [4,4096,1024] f32; Wk/Wq/Wv [128,1024] f32.
// out = causal_softmax((emb Wq^T)(emb Wk^T)^T / sqrt(128)) (emb Wv^T), f32.
//
// R12: attn staged via ASYNC __builtin_amdgcn_global_load_lds (width=16) from
// frag-ordered Kf/Vf (source and LDS dest both linear in tid -> satisfies the
// wave-uniform-base + lane*16 constraint exactly). Double-buffered 32KB tiles,
// one barrier/iter (its vmcnt(0) drain IS the async wait), fixed-ref softmax.
// R7-R11 established: all register/LDS staging variants plateau 71-84us with
// every counted pipe <16%; this removes the staging VGPR round-trip + VALU.
// Frag layouts (HW-verified R2-R11): A/B frag idx=lane&15, k=quad*8+j (K=32)
// or quad*4+j (K=16); D col(lane&15)=B's n, row(quad*4+reg)=A's m.
//  Qf/Kf[((b*256 + s16)*4 + kf)*64 + lane] x bf16x8   (s16 = seq/16)
//  Vf[(((b*64 + kt)*8 + ht)*4 + nt)*64 + lane] x f16x4 (kt = seq/64)

#define SEQ 4096
#define BATCH 4
#define HS 128
#define PSTRIDE ((size_t)BATCH * SEQ * HS)   // u16 elems per split partial

typedef unsigned short u16;
typedef __bf16 bf16x8 __attribute__((ext_vector_type(8)));
typedef _Float16 f16x4 __attribute__((ext_vector_type(4)));
typedef float f32x4 __attribute__((ext_vector_type(4)));

__device__ __forceinline__ u16 f2bf(float f) {
    union { float f; unsigned u; } v; v.f = f;
    unsigned u = v.u;
    return (u16)((u + 0x7FFFu + ((u >> 16) & 1u)) >> 16);  // RNE, finite
}
__device__ __forceinline__ float bf2f(u16 u) {
    union { unsigned u; float f; } v; v.u = ((unsigned)u) << 16; return v.f;
}
__device__ __forceinline__ u16 f2h(float f) {
    union { _Float16 h; u16 u; } v; v.h = (_Float16)f; return v.u;
}
// async 16B global->LDS DMA: LDS dest = wave-uniform base + lane*16
__device__ __forceinline__ void async_cp16(const void* g, void* l) {
    __builtin_amdgcn_global_load_lds(
        (const __attribute__((address_space(1))) unsigned int*)g,
        (__attribute__((address_space(3))) unsigned int*)l, 16, 0, 0);
}

// ---------------- K0: W -> bf16, pre-tiled in B-frag order ----------------
__global__ __launch_bounds__(256) void wconv_kernel(
    const float* __restrict__ Wk, const float* __restrict__ Wq,
    const float* __restrict__ Wv, u16* __restrict__ Wt)
{
    const int g    = blockIdx.x * 256 + threadIdx.x;   // 0..49151
    const int lane = g & 63;
    const int kf   = (g >> 6) & 1;
    const int kc   = (g >> 7) & 15;
    const int nt   = g >> 11;
    const int row  = nt * 16 + (lane & 15);
    const int k0   = kc * 64 + kf * 32 + (lane >> 4) * 8;
    const float* src = (row < 128) ? Wk : ((row < 256) ? Wq : Wv);
    const float scale = (row >= 128 && row < 256)
        ? 0.08838834764831845f * 1.4426950408889634f : 1.0f;
    const float4 v0 = *(const float4*)&src[(size_t)(row & 127) * 1024 + k0];
    const float4 v1 = *(const float4*)&src[(size_t)(row & 127) * 1024 + k0 + 4];
    ushort4 a, b;
    a.x = f2bf(v0.x * scale); a.y = f2bf(v0.y * scale);
    a.z = f2bf(v0.z * scale); a.w = f2bf(v0.w * scale);
    b.x = f2bf(v1.x * scale); b.y = f2bf(v1.y * scale);
    b.z = f2bf(v1.z * scale); b.w = f2bf(v1.w * scale);
    *(ushort4*)&Wt[(size_t)g * 8]     = a;
    *(ushort4*)&Wt[(size_t)g * 8 + 4] = b;
}

// ---------------- K1: QKV projection -> frag-ordered outputs ----------------
// grid 512 x 256 (2 blocks/CU). Block: 32 emb rows x 384 cols; wave: 96 cols.
__global__ __launch_bounds__(256, 2) void qkv_kernel(
    const float* __restrict__ emb, const u16* __restrict__ Wt,
    u16* __restrict__ Qf, u16* __restrict__ Kf, u16* __restrict__ Vf)
{
    __shared__ u16 sE[2][32][72];
    __shared__ u16 sOut[32][392];   // cols 0-127 K(bf16), 128-255 Q(bf16), 256-383 V(f16)

    const int tid  = threadIdx.x;
    const int wv   = tid >> 6;
    const int lane = tid & 63;
    const int quad = lane >> 4;
    const int l16  = lane & 15;
    const int R0   = blockIdx.x * 32;

    const int arow = tid >> 3, ac8 = tid & 7;     // A-stage: 16B/thread/chunk
    const float* abase = &emb[(size_t)(R0 + arow) * 1024 + ac8 * 8];

    f32x4 acc[2][6];
    #pragma unroll
    for (int rg = 0; rg < 2; rg++)
        #pragma unroll
        for (int nt = 0; nt < 6; nt++) acc[rg][nt] = (f32x4){0.f, 0.f, 0.f, 0.f};

    bf16x8 B0[12], B1[12];

#define LOADB(kci, B)                                                          \
    {                                                                          \
        _Pragma("unroll")                                                      \
        for (int nt = 0; nt < 6; nt++) {                                       \
            const size_t g = ((size_t)((wv * 6 + nt) * 16 + (kci)) * 2) * 64 + lane; \
            B[2 * nt]     = *(const bf16x8*)&Wt[g * 8];                        \
            B[2 * nt + 1] = *(const bf16x8*)&Wt[(g + 64) * 8];                 \
        }                                                                      \
    }
#define WRITEA(buf, v0, v1)                                                    \
    {                                                                          \
        ushort4 lo, hi;                                                        \
        lo.x = f2bf((v0).x); lo.y = f2bf((v0).y);                              \
        lo.z = f2bf((v0).z); lo.w = f2bf((v0).w);                              \
        hi.x = f2bf((v1).x); hi.y = f2bf((v1).y);                              \
        hi.z = f2bf((v1).z); hi.w = f2bf((v1).w);                              \
        *(ushort4*)&sE[buf][arow][ac8 * 8]     = lo;                           \
        *(ushort4*)&sE[buf][arow][ac8 * 8 + 4] = hi;                           \
    }
#define COMPUTE(buf, B)                                                        \
    {                                                                          \
        bf16x8 a[2][2];                                                        \
        _Pragma("unroll")                                                      \
        for (int rg = 0; rg < 2; rg++)                                         \
            _Pragma("unroll")                                                  \
            for (int kf = 0; kf < 2; kf++)                                     \
                a[rg][kf] = *(const bf16x8*)&sE[buf][rg * 16 + l16][kf * 32 + quad * 8]; \
        _Pragma("unroll")                                                      \
        for (int nt = 0; nt < 6; nt++)                                         \
            _Pragma("unroll")                                                  \
            for (int rg = 0; rg < 2; rg++) {                                   \
                acc[rg][nt] = __builtin_amdgcn_mfma_f32_16x16x32_bf16(a[rg][0], B[2 * nt],     acc[rg][nt], 0, 0, 0); \
                acc[rg][nt] = __builtin_amdgcn_mfma_f32_16x16x32_bf16(a[rg][1], B[2 * nt + 1], acc[rg][nt], 0, 0, 0); \
            }                                                                  \
    }

    float4 av0 = *(const float4*)&abase[0];
    float4 av1 = *(const float4*)&abase[4];
    LOADB(0, B0);
    WRITEA(0, av0, av1);

    for (int it = 0; it < 8; it++) {
        const int k1 = 2 * it + 1;
        __syncthreads();
        av0 = *(const float4*)&abase[k1 * 64];
        av1 = *(const float4*)&abase[k1 * 64 + 4];
        LOADB(k1, B1);
        COMPUTE(0, B0);
        WRITEA(1, av0, av1);
        __syncthreads();
        if (it < 7) {
            av0 = *(const float4*)&abase[(k1 + 1) * 64];
            av1 = *(const float4*)&abase[(k1 + 1) * 64 + 4];
            LOADB(k1 + 1, B0);
        }
        COMPUTE(1, B1);
        if (it < 7) WRITEA(0, av0, av1);
    }

    // ---- epilogue: acc -> sOut scatter -> frag-ordered coalesced stores ----
    #pragma unroll
    for (int nt = 0; nt < 6; nt++) {
        const int col = wv * 96 + nt * 16 + l16;
        #pragma unroll
        for (int rg = 0; rg < 2; rg++) {
            const int rl = rg * 16 + quad * 4;
            #pragma unroll
            for (int r = 0; r < 4; r++) {
                const float v = acc[rg][nt][r];
                sOut[rl + r][col] = (col < 256) ? f2bf(v) : f2h(v);
            }
        }
    }
    __syncthreads();

    const int b  = R0 >> 12;
    const int s0 = R0 & 4095;
    // K and Q frag-order: bf16x8 groups, contiguous 1KB wave stores
    #pragma unroll
    for (int i = 0; i < 2; i++) {
        const int g    = tid + i * 256;          // 0..511
        const int lg   = g & 63;
        const int kfp  = (g >> 6) & 3;
        const int k16l = g >> 8;                 // 0..1
        const int rl   = k16l * 16 + (lg & 15);
        const int cl   = kfp * 32 + (lg >> 4) * 8;
        const size_t base = (((size_t)(b * 256 + (s0 >> 4) + k16l) * 4 + kfp) * 64 + lg) * 8;
        *(uint4*)&Kf[base] = *(const uint4*)&sOut[rl][cl];
        *(uint4*)&Qf[base] = *(const uint4*)&sOut[rl][128 + cl];
    }
    // V frag-order: f16x4 groups, contiguous 512B wave stores
    #pragma unroll
    for (int i = 0; i < 4; i++) {
        const int g   = tid + i * 256;           // 0..1023
        const int lg  = g & 63;
        const int ntl = (g >> 6) & 1;
        const int ht  = g >> 7;                  // 0..7
        const int h   = ht * 16 + (lg & 15);
        const int kl  = ntl * 16 + ((lg >> 4) & 3) * 4;
        ushort4 o;
        o.x = sOut[kl + 0][256 + h];
        o.y = sOut[kl + 1][256 + h];
        o.z = sOut[kl + 2][256 + h];
        o.w = sOut[kl + 3][256 + h];
        const int t64 = s0 >> 6;
        const int ntg = ((s0 >> 4) & 3) + ntl;
        const size_t base = ((((size_t)(b * 64 + t64) * 8 + ht) * 4 + ntg) * 64 + lg) * 4;
        *(ushort4*)&Vf[base] = o;
    }
#undef LOADB
#undef WRITEA
#undef COMPUTE
}

// ---------------- K2: async-staged dbuf flash attention ----------------
// grid 32*BATCH*SPLIT x 256 (SPLIT=4: 512 blocks = 2/CU). 128 q rows/block.
// 32KB tile (K 16KB frag-order + V 16KB frag-order) staged by 8 async 16B
// DMAs/thread; barrier's vmcnt(0) drain is the wait. Fixed-ref softmax.
template<int SPLIT>
__global__ __launch_bounds__(256, 2) void attn_kernel(
    const u16* __restrict__ Qf, const u16* __restrict__ Kf,
    const u16* __restrict__ Vf, u16* __restrict__ Opart,
    float* __restrict__ lpart, float* __restrict__ out)
{
    __shared__ u16 sT[2][16384];   // [buf]: 0-8191 K-frags, 8192-16383 V-frags

    const int tid  = threadIdx.x;
    const int wv   = tid >> 6;
    const int lane = tid & 63;
    const int quad = lane >> 4;
    const int l16  = lane & 15;

    const int L = blockIdx.x;
    const int b = L & 3;
    const int u = L >> 2;
    int Q, sp;
    if constexpr (SPLIT == 1) {
        Q = u; sp = 0;
    } else {
        constexpr int half = SPLIT / 2;
        if (u < 32 * half) { Q = u / half; sp = u % half; }
        else { const int v = u - 32 * half; Q = 31 - v / half; sp = half + v % half; }
    }
    const int q0 = Q * 128;
    const int ktmax = 2 * Q + 1;
    const size_t bS = (size_t)b * SEQ;

    const char* KbB = (const char*)(Kf + (size_t)b * 524288);  // per-kt: 16KB
    const char* VbB = (const char*)(Vf + (size_t)b * 524288);  // per-kt: 16KB

    // Q fragments from frag-ordered Qf (coalesced 1KB wave loads)
    bf16x8 qf[2][4];
    #pragma unroll
    for (int qg = 0; qg < 2; qg++) {
        const int q16 = Q * 8 + wv * 2 + qg;
        #pragma unroll
        for (int kf = 0; kf < 4; kf++)
            qf[qg][kf] = *(const bf16x8*)&Qf[(((size_t)(b * 256 + q16) * 4 + kf) * 64 + lane) * 8];
    }

    float rs0 = 0.f, rs1 = 0.f;
    f32x4 O[2][8];   // O^T: col=q=l16, row=h=ht*16+quad*4+reg
    #pragma unroll
    for (int qg = 0; qg < 2; qg++)
        #pragma unroll
        for (int ht = 0; ht < 8; ht++) O[qg][ht] = (f32x4){0.f, 0.f, 0.f, 0.f};

    const int qg0 = q0 + wv * 32 + l16;   // qg=1 row is qg0+16

    // async stage of tile kt into buffer buf (linear 32KB copy)
    const int lseg = wv * 1024 + lane * 16;   // per-thread source byte offset
#define STAGE(bufi, kt)                                                        \
    {                                                                          \
        const char* ks = KbB + (size_t)(kt) * 16384;                           \
        const char* vs = VbB + (size_t)(kt) * 16384;                           \
        char* lb = (char*)&sT[bufi][0] + wv * 1024;                            \
        _Pragma("unroll")                                                      \
        for (int i = 0; i < 4; i++)                                            \
            async_cp16(ks + i * 4096 + lseg, lb + i * 4096);                   \
        _Pragma("unroll")                                                      \
        for (int i = 0; i < 4; i++)                                            \
            async_cp16(vs + i * 4096 + lseg, lb + 16384 + i * 4096);           \
    }

    STAGE(0, sp);
    __syncthreads();   // vmcnt(0) drain completes the async copies

    int buf = 0;
    for (int kt = sp; kt <= ktmax; kt += SPLIT) {
        const int kb = kt * 64;
        if (kt + SPLIT <= ktmax) STAGE(buf ^ 1, kt + SPLIT);  // fly during compute

        const bool diag = (kt >= 2 * Q);
        f16x4 pf0[4], pf1[4];
        #pragma unroll
        for (int nt = 0; nt < 4; nt++) {   // stream S-tile -> p
            f32x4 s0 = (f32x4){0.f, 0.f, 0.f, 0.f};
            f32x4 s1 = (f32x4){0.f, 0.f, 0.f, 0.f};
            #pragma unroll
            for (int kf = 0; kf < 4; kf++) {
                const bf16x8 kfr = *(const bf16x8*)&sT[buf][((nt * 4 + kf) << 9) + lane * 8];
                s0 = __builtin_amdgcn_mfma_f32_16x16x32_bf16(kfr, qf[0][kf], s0, 0, 0, 0);
                s1 = __builtin_amdgcn_mfma_f32_16x16x32_bf16(kfr, qf[1][kf], s1, 0, 0, 0);
            }
            if (diag) {
                #pragma unroll
                for (int r = 0; r < 4; r++) {
                    const int kg = kb + nt * 16 + quad * 4 + r;
                    if (kg > qg0)      s0[r] = -3.0e38f;
                    if (kg > qg0 + 16) s1[r] = -3.0e38f;
                }
            }
            f16x4 p0, p1;
            #pragma unroll
            for (int r = 0; r < 4; r++) {
                const float e0 = exp2f(s0[r] - 4.0f);   // scores in log2 domain
                const float e1 = exp2f(s1[r] - 4.0f);
                rs0 += e0; rs1 += e1;
                p0[r] = (_Float16)e0; p1[r] = (_Float16)e1;
            }
            pf0[nt] = p0; pf1[nt] = p1;
        }

        // O^T += V^T·P^T
        #pragma unroll
        for (int ht = 0; ht < 8; ht++) {
            f16x4 vf[4];
            #pragma unroll
            for (int nt = 0; nt < 4; nt++)
                vf[nt] = *(const f16x4*)&sT[buf][8192 + ((ht * 4 + nt) << 8) + lane * 4];
            #pragma unroll
            for (int nt = 0; nt < 4; nt++) {
                O[0][ht] = __builtin_amdgcn_mfma_f32_16x16x16f16(vf[nt], pf0[nt], O[0][ht], 0, 0, 0);
                O[1][ht] = __builtin_amdgcn_mfma_f32_16x16x16f16(vf[nt], pf1[nt], O[1][ht], 0, 0, 0);
            }
        }

        __syncthreads();   // drains next-tile DMAs; orders buffer reuse
        buf ^= 1;
    }
#undef STAGE

    rs0 += __shfl_xor(rs0, 16); rs0 += __shfl_xor(rs0, 32);
    rs1 += __shfl_xor(rs1, 16); rs1 += __shfl_xor(rs1, 32);

    if constexpr (SPLIT == 1) {
        #pragma unroll
        for (int qg = 0; qg < 2; qg++) {
            const float inv = 1.0f / (qg ? rs1 : rs0);
            const int q = q0 + wv * 32 + qg * 16 + l16;
            #pragma unroll
            for (int ht = 0; ht < 8; ht++) {
                f32x4 o = O[qg][ht] * inv;
                *(f32x4*)&out[(bS + q) * HS + ht * 16 + quad * 4] = o;
            }
        }
    } else {
        // register-order slots: each wave store = 512B contiguous
        #pragma unroll
        for (int qg = 0; qg < 2; qg++)
            #pragma unroll
            for (int ht = 0; ht < 8; ht++) {
                const size_t j = ((size_t)((((b * 32 + Q) * 4 + wv) * 2 + qg) * 8 + ht)) * 64 + lane;
                ushort4 o;
                o.x = f2bf(O[qg][ht][0]); o.y = f2bf(O[qg][ht][1]);
                o.z = f2bf(O[qg][ht][2]); o.w = f2bf(O[qg][ht][3]);
                *(ushort4*)&Opart[(size_t)sp * PSTRIDE + j * 4] = o;
            }
        if (quad == 0) {
            lpart[((size_t)(sp * BATCH + b)) * SEQ + q0 + wv * 32 + l16]      = rs0;
            lpart[((size_t)(sp * BATCH + b)) * SEQ + q0 + wv * 32 + 16 + l16] = rs1;
        }
    }
}

// ---------------- K3: merge split partials ----------------
template<int SPLIT>
__global__ __launch_bounds__(256) void merge_kernel(
    const u16* __restrict__ Opart, const float* __restrict__ lpart,
    float* __restrict__ out)
{
    const int g  = blockIdx.x * 256 + threadIdx.x;   // one float4 of out
    const int b  = g >> 17;
    const int q  = (g >> 5) & 4095;
    const int hc = g & 31;
    const int Qb = q >> 7, wvv = (q >> 5) & 3, qg = (q >> 4) & 1, l16 = q & 15;
    const int ht = hc >> 2, qd = hc & 3;
    const int lane = qd * 16 + l16;
    const size_t j4 = (((size_t)((((b * 32 + Qb) * 4 + wvv) * 2 + qg) * 8 + ht)) * 64 + lane) * 4;

    float den = 0.f;
    f32x4 num = (f32x4){0.f, 0.f, 0.f, 0.f};
    #pragma unroll
    for (int s = 0; s < SPLIT; s++) {
        den += lpart[((size_t)(s * BATCH + b)) * SEQ + q];
        const ushort4 o = *(const ushort4*)&Opart[(size_t)s * PSTRIDE + j4];
        num[0] += bf2f(o.x); num[1] += bf2f(o.y);
        num[2] += bf2f(o.z); num[3] += bf2f(o.w);
    }
    const float inv = 1.0f / den;
    float4 o; o.x = num[0] * inv; o.y = num[1] * inv;
    o.z = num[2] * inv; o.w = num[3] * inv;
    *(float4*)&out[(size_t)g * 4] = o;
}

extern "C" void kernel_launch(void* const* d_in, const int* in_sizes, int n_in,
                              void* d_out, int out_size, void* d_ws, size_t ws_size,
                              hipStream_t stream) {
    const float* emb = (const float*)d_in[0];
    const float* Wk  = (const float*)d_in[1];
    const float* Wq  = (const float*)d_in[2];
    const float* Wv  = (const float*)d_in[3];
    float* out = (float*)d_out;

    char* ws = (char*)d_ws;
    const size_t WBF_SZ    = (size_t)384 * 1024 * 2;
    const size_t QKV_SZ    = (size_t)BATCH * SEQ * HS * 2;   // 4 MB each
    const size_t Q_OFF     = WBF_SZ;
    const size_t K_OFF     = Q_OFF + QKV_SZ;
    const size_t V_OFF     = K_OFF + QKV_SZ;
    const size_t OPART_OFF = V_OFF + QKV_SZ;
    const size_t OPART_1   = PSTRIDE * 2;                    // 4 MB per split
    const size_t L_1       = (size_t)BATCH * SEQ * 4;        // 64 KB per split

    u16* Wt = (u16*)ws;
    u16* Qf = (u16*)(ws + Q_OFF);
    u16* Kf = (u16*)(ws + K_OFF);
    u16* Vf = (u16*)(ws + V_OFF);

    wconv_kernel<<<dim3(192), dim3(256), 0, stream>>>(Wk, Wq, Wv, Wt);
    qkv_kernel<<<dim3(512), dim3(256), 0, stream>>>(emb, Wt, Qf, Kf, Vf);

    const size_t need4 = OPART_OFF + 4 * (OPART_1 + L_1);
    const size_t need2 = OPART_OFF + 2 * (OPART_1 + L_1);

    if (ws_size >= need4) {
        u16*   Opart = (u16*)(ws + OPART_OFF);
        float* lp    = (float*)(ws + OPART_OFF + 4 * OPART_1);
        attn_kernel<4><<<dim3(32 * BATCH * 4), dim3(256), 0, stream>>>(Qf, Kf, Vf, Opart, lp, out);
        merge_kernel<4><<<dim3(BATCH * SEQ * HS / 4 / 256), dim3(256), 0, stream>>>(Opart, lp, out);
    } else if (ws_size >= need2) {
        u16*   Opart = (u16*)(ws + OPART_OFF);
        float* lp    = (float*)(ws + OPART_OFF + 2 * OPART_1);
        attn_kernel<2><<<dim3(32 * BATCH * 2), dim3(256), 0, stream>>>(Qf, Kf, Vf, Opart, lp, out);
        merge_kernel<2><<<dim3(BATCH * SEQ * HS / 4 / 256), dim3(256), 0, stream>>>(Opart, lp, out);
    } else {
        attn_kernel<1><<<dim3(32 * BATCH), dim3(256), 0, stream>>>(Qf, Kf, Vf, nullptr, nullptr, out);
    }
}